// Round 12
// baseline (129.148 us; speedup 1.0000x reference)
//
#include <hip/hip_runtime.h>

// Problem constants (from reference)
#define NS   1000        // N_SAMPLES
#define NB   32          // batch
#define NK   27          // cluster channels
#define KP   28          // padded K (for float4)
#define HW   65536       // 256*256
// sim = 10*exp(-cd/1.0 - gd/0.3) + 3*exp(-cd/0.1)

// ws layout (floats):
//   selc [NB][NS][KP]  : 896000
//   selg [NB][NS][4]   : 128000   (offset 896000)
//   cf   [NS][2]       : 2000     (offset 1024000)
#define OFF_SELG 896000
#define OFF_CF   1024000

// gather: one thread per (n, i, ch), ch in [0,32)
__global__ void crf_gather(const float* __restrict__ guidance,
                           const float* __restrict__ clusters,
                           const int* __restrict__ coords,
                           float* __restrict__ ws) {
    int tid = blockIdx.x * 256 + threadIdx.x;
    if (tid >= NB * NS * 32) return;
    int ch = tid & 31;
    int ni = tid >> 5;
    int n = ni / NS;
    int i = ni - n * NS;
    int r = coords[i];
    int c = coords[NS + i];
    int pix = r * 256 + c;

    if (ch < KP) {
        float v = 0.0f;
        if (ch < NK)
            v = clusters[((long)n * NK + ch) * HW + pix];
        ws[(long)ni * KP + ch] = v;
    } else {
        int g = ch - KP;  // 0..3
        float v = 0.0f;
        if (g < 3)
            v = guidance[((long)n * 3 + g) * HW + pix];
        ws[OFF_SELG + (long)ni * 4 + g] = v;
        if (g == 3 && n == 0) {
            ws[OFF_CF + i * 2]     = (float)r;
            ws[OFF_CF + i * 2 + 1] = (float)c;
        }
    }
}

#define RA     20          // a-rows per block
#define NCHUNK 50          // NS / RA

// main: R11 verbatim (prefetched a-row double buffer)
__global__ __launch_bounds__(512, 4) void crf_main(const float* __restrict__ ws,
                                                   float* __restrict__ out) {
    const int bid = blockIdx.x;
    const int n = bid / NCHUNK;
    const int a0 = (bid - n * NCHUNK) * RA;
    const int t = threadIdx.x;

    const float* __restrict__ selc = ws;
    const float* __restrict__ selg = ws + OFF_SELG;
    const float* __restrict__ cf   = ws + OFF_CF;

    const int b0 = t;
    const int b1raw = t + 512;
    const int b1 = b1raw < NS ? b1raw : NS - 1;

    float4 cb[2][7];
    float gb0[2], gb1[2], gb2[2], xbr[2], xbc[2];
    {
        const int bs[2] = {b0, b1};
        #pragma unroll
        for (int i = 0; i < 2; ++i) {
            const float4* pc = (const float4*)(selc + ((long)n * NS + bs[i]) * KP);
            #pragma unroll
            for (int j = 0; j < 7; ++j) cb[i][j] = pc[j];
            const float* pg = selg + ((long)n * NS + bs[i]) * 4;
            gb0[i] = pg[0]; gb1[i] = pg[1]; gb2[i] = pg[2];
            xbr[i] = cf[bs[i] * 2]; xbc[i] = cf[bs[i] * 2 + 1];
        }
    }

    const bool w1 = (b1raw < NS);

    float4 pa_nx[7];
    float ga0_nx, ga1_nx, ga2_nx, xar_nx, xac_nx;
    {
        const long arow = (long)n * NS + a0;
        const float4* pa = (const float4*)(selc + arow * KP);
        #pragma unroll
        for (int j = 0; j < 7; ++j) pa_nx[j] = pa[j];
        const float* pg = selg + arow * 4;
        ga0_nx = pg[0]; ga1_nx = pg[1]; ga2_nx = pg[2];
        xar_nx = cf[a0 * 2]; xac_nx = cf[a0 * 2 + 1];
    }

    for (int a = 0; a < RA; ++a) {
        float4 pa_cur[7];
        #pragma unroll
        for (int j = 0; j < 7; ++j) pa_cur[j] = pa_nx[j];
        const float ga0 = ga0_nx, ga1 = ga1_nx, ga2 = ga2_nx;
        const float xar = xar_nx, xac = xac_nx;

        if (a < RA - 1) {
            const long arow = (long)n * NS + a0 + a + 1;
            const float4* pa = (const float4*)(selc + arow * KP);
            #pragma unroll
            for (int j = 0; j < 7; ++j) pa_nx[j] = pa[j];
            const float* pg = selg + arow * 4;
            ga0_nx = pg[0]; ga1_nx = pg[1]; ga2_nx = pg[2];
            xar_nx = cf[(a0 + a + 1) * 2]; xac_nx = cf[(a0 + a + 1) * 2 + 1];
        }

        float dot0 = 0.0f, dot1 = 0.0f;
        #pragma unroll
        for (int j = 0; j < 7; ++j) {
            float4 va = pa_cur[j];
            dot0 += va.x * cb[0][j].x;  dot1 += va.x * cb[1][j].x;
            dot0 += va.y * cb[0][j].y;  dot1 += va.y * cb[1][j].y;
            dot0 += va.z * cb[0][j].z;  dot1 += va.z * cb[1][j].z;
            dot0 += va.w * cb[0][j].w;  dot1 += va.w * cb[1][j].w;
        }

        float* po = out + ((long)n * NS + a0 + a) * NS;
        {
            float g0 = ga0 - gb0[0], g1 = ga1 - gb1[0], g2 = ga2 - gb2[0];
            float gd = g0 * g0 + g1 * g1 + g2 * g2;
            float dr = xar - xbr[0], dc = xac - xbc[0];
            float cd = dr * dr + dc * dc;
            float s = 10.0f * __expf(-cd - gd * (1.0f / 0.3f))
                    +  3.0f * __expf(-10.0f * cd);
            po[b0] = -dot0 * s;
        }
        {
            float g0 = ga0 - gb0[1], g1 = ga1 - gb1[1], g2 = ga2 - gb2[1];
            float gd = g0 * g0 + g1 * g1 + g2 * g2;
            float dr = xar - xbr[1], dc = xac - xbc[1];
            float cd = dr * dr + dc * dc;
            float s = 10.0f * __expf(-cd - gd * (1.0f / 0.3f))
                    +  3.0f * __expf(-10.0f * cd);
            if (w1) po[b1raw] = -dot1 * s;
        }
    }
}

extern "C" void kernel_launch(void* const* d_in, const int* in_sizes, int n_in,
                              void* d_out, int out_size, void* d_ws, size_t ws_size,
                              hipStream_t stream) {
    const float* guidance = (const float*)d_in[0];
    const float* clusters = (const float*)d_in[1];
    const int*   coords   = (const int*)d_in[2];
    float* out = (float*)d_out;
    float* ws  = (float*)d_ws;

    {
        int total = NB * NS * 32;
        int blocks = (total + 255) / 256;
        crf_gather<<<blocks, 256, 0, stream>>>(guidance, clusters, coords, ws);
    }
    // MEASUREMENT ROUND 2: main launched TWICE (idempotent — same ws -> same
    // out). M = dur_us - 76.5, G = 76.5 - M, with no cache-warmth assumption.
    {
        int blocks = NB * NCHUNK;   // 1600
        crf_main<<<blocks, 512, 0, stream>>>(ws, out);
        crf_main<<<blocks, 512, 0, stream>>>(ws, out);
    }
}

// Round 13
// 103.455 us; speedup vs baseline: 1.2484x; 1.2484x over previous
//
#include <hip/hip_runtime.h>

// Problem constants (from reference)
#define NS   1000        // N_SAMPLES
#define NB   32          // batch
#define NK   27          // cluster channels
#define KP   28          // padded K (for float4)
#define HW   65536       // 256*256
#define OUT_FLOATS 32000000   // NB*NS*NS
// sim = 10*exp(-cd/1.0 - gd/0.3) + 3*exp(-10*cd)
// KEY: coords random in 256^2 => cd >= 30 for 99.8% of pairs => sim
// underflows (max |masked| <= 10*|dot|*e^-30 ~ 8e-10 << threshold 16.88).
// Output = zeros + ~2800 sparse (a,b) pairs x 32 batches.

// ws layout (floats):
//   selc [NB][NS][KP]  : 896000
//   selg [NB][NS][4]   : 128000   (offset 896000)
//   cf   [NS][2]       : 2000     (offset 1024000)
#define OFF_SELG 896000
#define OFF_CF   1024000

// ---- K1: fused gather (even blocks) + output zero-fill (odd blocks) ----
__global__ __launch_bounds__(256) void crf_gather_fill(
        const float* __restrict__ guidance,
        const float* __restrict__ clusters,
        const int* __restrict__ coords,
        float* __restrict__ ws,
        float* __restrict__ out) {
    const int bid = blockIdx.x;
    int role, unit;
    if (bid < 8000) { role = bid & 1; unit = bid >> 1; }
    else           { role = 1;       unit = bid - 8000 + 4000; }

    if (role == 0) {
        // gather unit in [0,4000): R10-proven mapping, tid per (n,i,ch)
        int tid = unit * 256 + threadIdx.x;      // < 1,024,000 = NB*NS*32
        int ch = tid & 31;
        int ni = tid >> 5;
        int n = ni / NS;
        int i = ni - n * NS;
        int r = coords[i];
        int c = coords[NS + i];
        int pix = r * 256 + c;

        if (ch < KP) {
            float v = 0.0f;
            if (ch < NK)
                v = clusters[((long)n * NK + ch) * HW + pix];
            ws[(long)ni * KP + ch] = v;
        } else {
            int g = ch - KP;  // 0..3
            float v = 0.0f;
            if (g < 3)
                v = guidance[((long)n * 3 + g) * HW + pix];
            ws[OFF_SELG + (long)ni * 4 + g] = v;
            if (g == 3 && n == 0) {
                ws[OFF_CF + i * 2]     = (float)r;
                ws[OFF_CF + i * 2 + 1] = (float)c;
            }
        }
    } else {
        // fill unit in [0,4096): zero a contiguous 32KB chunk of out
        long base = (long)unit * 8192 + threadIdx.x * 4;
        float4 z = {0.0f, 0.0f, 0.0f, 0.0f};
        #pragma unroll
        for (int k = 0; k < 8; ++k) {
            long idx = base + (long)k * 1024;
            if (idx < OUT_FLOATS)
                *(float4*)(out + idx) = z;
        }
    }
}

// ---- K2: sparse compute — one lane per (a,b) pair, skip if cd >= 30 ----
__global__ __launch_bounds__(256) void crf_sparse(const float* __restrict__ ws,
                                                  float* __restrict__ out) {
    int pair = blockIdx.x * 256 + threadIdx.x;
    if (pair >= NS * NS) return;
    int a = pair / NS;
    int b = pair - a * NS;

    const float* __restrict__ cf = ws + OFF_CF;
    float dr = cf[2 * a]     - cf[2 * b];
    float dc = cf[2 * a + 1] - cf[2 * b + 1];
    float cd = dr * dr + dc * dc;
    if (cd >= 30.0f) return;          // sim underflows; out stays 0

    const float* __restrict__ selc = ws;
    const float* __restrict__ selg = ws + OFF_SELG;
    const float e2 = 3.0f * __expf(-10.0f * cd);

    for (int n = 0; n < NB; ++n) {
        const float4* pa4 = (const float4*)(selc + ((long)n * NS + a) * KP);
        const float4* pb4 = (const float4*)(selc + ((long)n * NS + b) * KP);
        float dot = 0.0f;
        #pragma unroll
        for (int j = 0; j < 7; ++j) {
            float4 va = pa4[j], vb = pb4[j];
            dot += va.x * vb.x;
            dot += va.y * vb.y;
            dot += va.z * vb.z;
            dot += va.w * vb.w;
        }
        const float* ga = selg + ((long)n * NS + a) * 4;
        const float* gb = selg + ((long)n * NS + b) * 4;
        float g0 = ga[0] - gb[0], g1 = ga[1] - gb[1], g2 = ga[2] - gb[2];
        float gd = g0 * g0 + g1 * g1 + g2 * g2;
        float s = 10.0f * __expf(-cd - gd * (1.0f / 0.3f)) + e2;
        out[((long)n * NS + a) * NS + b] = -dot * s;
    }
}

extern "C" void kernel_launch(void* const* d_in, const int* in_sizes, int n_in,
                              void* d_out, int out_size, void* d_ws, size_t ws_size,
                              hipStream_t stream) {
    const float* guidance = (const float*)d_in[0];
    const float* clusters = (const float*)d_in[1];
    const int*   coords   = (const int*)d_in[2];
    float* out = (float*)d_out;
    float* ws  = (float*)d_ws;

    // K1: 4000 gather blocks interleaved with 4096 fill blocks
    crf_gather_fill<<<8096, 256, 0, stream>>>(guidance, clusters, coords, ws, out);
    // K2: 1e6 pair lanes, ~0.2% take the heavy path
    crf_sparse<<<(NS * NS + 255) / 256, 256, 0, stream>>>(ws, out);
}

// Round 14
// 61.443 us; speedup vs baseline: 2.1019x; 1.6838x over previous
//
#include <hip/hip_runtime.h>

// Problem constants (from reference)
#define NS   1000        // N_SAMPLES
#define NB   32          // batch
#define NK   27          // cluster channels
#define KP   28          // padded K (for float4)
#define HW   65536       // 256*256
// sim = 10*exp(-cd/1.0 - gd/0.3) + 3*exp(-10*cd)
// SPARSITY (validated R13): coords random in 256^2 => for cd >= 30 sim
// underflows (|masked| <= ~1e-9 << threshold 16.88) => emit exact 0 and
// skip the dot/exp for 99.7% of pairs. Store pattern unchanged from R11.

// ws layout (floats):
//   selc [NB][NS][KP]  : 896000
//   selg [NB][NS][4]   : 128000   (offset 896000)
//   cf   [NS][2]       : 2000     (offset 1024000)
#define OFF_SELG 896000
#define OFF_CF   1024000

// gather: one thread per (n, i, ch), ch in [0,32)  (R10 verbatim)
__global__ void crf_gather(const float* __restrict__ guidance,
                           const float* __restrict__ clusters,
                           const int* __restrict__ coords,
                           float* __restrict__ ws) {
    int tid = blockIdx.x * 256 + threadIdx.x;
    if (tid >= NB * NS * 32) return;
    int ch = tid & 31;
    int ni = tid >> 5;
    int n = ni / NS;
    int i = ni - n * NS;
    int r = coords[i];
    int c = coords[NS + i];
    int pix = r * 256 + c;

    if (ch < KP) {
        float v = 0.0f;
        if (ch < NK)
            v = clusters[((long)n * NK + ch) * HW + pix];
        ws[(long)ni * KP + ch] = v;
    } else {
        int g = ch - KP;  // 0..3
        float v = 0.0f;
        if (g < 3)
            v = guidance[((long)n * 3 + g) * HW + pix];
        ws[OFF_SELG + (long)ni * 4 + g] = v;
        if (g == 3 && n == 0) {
            ws[OFF_CF + i * 2]     = (float)r;
            ws[OFF_CF + i * 2 + 1] = (float)c;
        }
    }
}

#define RA     20          // a-rows per block
#define NCHUNK 50          // NS / RA

// main: R11 structure (prefetched a-row) + cd<30 sparsity gate per column.
__global__ __launch_bounds__(512, 4) void crf_main(const float* __restrict__ ws,
                                                   float* __restrict__ out) {
    const int bid = blockIdx.x;
    const int n = bid / NCHUNK;
    const int a0 = (bid - n * NCHUNK) * RA;
    const int t = threadIdx.x;

    const float* __restrict__ selc = ws;
    const float* __restrict__ selg = ws + OFF_SELG;
    const float* __restrict__ cf   = ws + OFF_CF;

    const int b0 = t;
    const int b1raw = t + 512;
    const int b1 = b1raw < NS ? b1raw : NS - 1;

    float4 cb[2][7];
    float gb0[2], gb1[2], gb2[2], xbr[2], xbc[2];
    {
        const int bs[2] = {b0, b1};
        #pragma unroll
        for (int i = 0; i < 2; ++i) {
            const float4* pc = (const float4*)(selc + ((long)n * NS + bs[i]) * KP);
            #pragma unroll
            for (int j = 0; j < 7; ++j) cb[i][j] = pc[j];
            const float* pg = selg + ((long)n * NS + bs[i]) * 4;
            gb0[i] = pg[0]; gb1[i] = pg[1]; gb2[i] = pg[2];
            xbr[i] = cf[bs[i] * 2]; xbc[i] = cf[bs[i] * 2 + 1];
        }
    }

    const bool w1 = (b1raw < NS);

    // prefetch a-row 0
    float4 pa_nx[7];
    float ga0_nx, ga1_nx, ga2_nx, xar_nx, xac_nx;
    {
        const long arow = (long)n * NS + a0;
        const float4* pa = (const float4*)(selc + arow * KP);
        #pragma unroll
        for (int j = 0; j < 7; ++j) pa_nx[j] = pa[j];
        const float* pg = selg + arow * 4;
        ga0_nx = pg[0]; ga1_nx = pg[1]; ga2_nx = pg[2];
        xar_nx = cf[a0 * 2]; xac_nx = cf[a0 * 2 + 1];
    }

    for (int a = 0; a < RA; ++a) {
        float4 pa_cur[7];
        #pragma unroll
        for (int j = 0; j < 7; ++j) pa_cur[j] = pa_nx[j];
        const float ga0 = ga0_nx, ga1 = ga1_nx, ga2 = ga2_nx;
        const float xar = xar_nx, xac = xac_nx;

        if (a < RA - 1) {
            const long arow = (long)n * NS + a0 + a + 1;
            const float4* pa = (const float4*)(selc + arow * KP);
            #pragma unroll
            for (int j = 0; j < 7; ++j) pa_nx[j] = pa[j];
            const float* pg = selg + arow * 4;
            ga0_nx = pg[0]; ga1_nx = pg[1]; ga2_nx = pg[2];
            xar_nx = cf[(a0 + a + 1) * 2]; xac_nx = cf[(a0 + a + 1) * 2 + 1];
        }

        float* po = out + ((long)n * NS + a0 + a) * NS;

        // ---- column 0 (sparsity-gated) ----
        {
            float dr = xar - xbr[0], dc = xac - xbc[0];
            float cd = dr * dr + dc * dc;
            float res = 0.0f;
            if (cd < 30.0f) {
                float dot = 0.0f;
                #pragma unroll
                for (int j = 0; j < 7; ++j) {
                    float4 va = pa_cur[j];
                    dot += va.x * cb[0][j].x;
                    dot += va.y * cb[0][j].y;
                    dot += va.z * cb[0][j].z;
                    dot += va.w * cb[0][j].w;
                }
                float g0 = ga0 - gb0[0], g1 = ga1 - gb1[0], g2 = ga2 - gb2[0];
                float gd = g0 * g0 + g1 * g1 + g2 * g2;
                float s = 10.0f * __expf(-cd - gd * (1.0f / 0.3f))
                        +  3.0f * __expf(-10.0f * cd);
                res = -dot * s;
            }
            po[b0] = res;
        }
        // ---- column 1 (sparsity-gated) ----
        {
            float dr = xar - xbr[1], dc = xac - xbc[1];
            float cd = dr * dr + dc * dc;
            float res = 0.0f;
            if (cd < 30.0f) {
                float dot = 0.0f;
                #pragma unroll
                for (int j = 0; j < 7; ++j) {
                    float4 va = pa_cur[j];
                    dot += va.x * cb[1][j].x;
                    dot += va.y * cb[1][j].y;
                    dot += va.z * cb[1][j].z;
                    dot += va.w * cb[1][j].w;
                }
                float g0 = ga0 - gb0[1], g1 = ga1 - gb1[1], g2 = ga2 - gb2[1];
                float gd = g0 * g0 + g1 * g1 + g2 * g2;
                float s = 10.0f * __expf(-cd - gd * (1.0f / 0.3f))
                        +  3.0f * __expf(-10.0f * cd);
                res = -dot * s;
            }
            if (w1) po[b1raw] = res;
        }
    }
}

extern "C" void kernel_launch(void* const* d_in, const int* in_sizes, int n_in,
                              void* d_out, int out_size, void* d_ws, size_t ws_size,
                              hipStream_t stream) {
    const float* guidance = (const float*)d_in[0];
    const float* clusters = (const float*)d_in[1];
    const int*   coords   = (const int*)d_in[2];
    float* out = (float*)d_out;
    float* ws  = (float*)d_ws;

    {
        int total = NB * NS * 32;
        int blocks = (total + 255) / 256;
        crf_gather<<<blocks, 256, 0, stream>>>(guidance, clusters, coords, ws);
    }
    {
        int blocks = NB * NCHUNK;   // 1600
        crf_main<<<blocks, 512, 0, stream>>>(ws, out);
    }
}

// Round 15
// 59.382 us; speedup vs baseline: 2.1749x; 1.0347x over previous
//
#include <hip/hip_runtime.h>

// Problem constants (from reference)
#define NS   1000        // N_SAMPLES
#define NB   32          // batch
#define NK   27          // cluster channels
#define KP   28          // padded K (for float4)
#define HW   65536       // 256*256
// sim = 10*exp(-cd/1.0 - gd/0.3) + 3*exp(-10*cd)
// SPARSITY (validated R13/R14): coords random in 256^2 => for cd >= 30 sim
// underflows (|masked| <= ~1e-9 << threshold 16.88) => emit exact 0 and skip
// everything (including row loads) for 99.7% of pairs.

// ws layout (floats):
//   selc [NB][NS][KP]  : 896000
//   selg [NB][NS][4]   : 128000   (offset 896000)
//   cf   [NS][2]       : 2000     (offset 1024000)
#define OFF_SELG 896000
#define OFF_CF   1024000

// gather: one thread per (n, i, ch), ch in [0,32)  (R10 verbatim)
__global__ void crf_gather(const float* __restrict__ guidance,
                           const float* __restrict__ clusters,
                           const int* __restrict__ coords,
                           float* __restrict__ ws) {
    int tid = blockIdx.x * 256 + threadIdx.x;
    if (tid >= NB * NS * 32) return;
    int ch = tid & 31;
    int ni = tid >> 5;
    int n = ni / NS;
    int i = ni - n * NS;
    int r = coords[i];
    int c = coords[NS + i];
    int pix = r * 256 + c;

    if (ch < KP) {
        float v = 0.0f;
        if (ch < NK)
            v = clusters[((long)n * NK + ch) * HW + pix];
        ws[(long)ni * KP + ch] = v;
    } else {
        int g = ch - KP;  // 0..3
        float v = 0.0f;
        if (g < 3)
            v = guidance[((long)n * 3 + g) * HW + pix];
        ws[OFF_SELG + (long)ni * 4 + g] = v;
        if (g == 3 && n == 0) {
            ws[OFF_CF + i * 2]     = (float)r;
            ws[OFF_CF + i * 2 + 1] = (float)c;
        }
    }
}

#define RA     20          // a-rows per block
#define NCHUNK 50          // NS / RA

// main: FULLY LAZY — unconditional work is only {cf loads, cd, gate, store}.
// All selc/selg row loads happen inside the cd<30 branch (~16% of waves).
// Register pressure ~40 VGPR -> high occupancy; TLP hides the rare load
// latency instead of an explicit prefetch pipeline.
__global__ __launch_bounds__(512) void crf_main(const float* __restrict__ ws,
                                                float* __restrict__ out) {
    const int bid = blockIdx.x;
    const int n = bid / NCHUNK;
    const int a0 = (bid - n * NCHUNK) * RA;
    const int t = threadIdx.x;

    const float* __restrict__ selc = ws;
    const float* __restrict__ selg = ws + OFF_SELG;
    const float* __restrict__ cf   = ws + OFF_CF;

    const int b0 = t;                       // < 1000 always
    const int b1raw = t + 512;
    const int b1 = b1raw < NS ? b1raw : NS - 1;
    const bool w1 = (b1raw < NS);

    const float xbr0 = cf[2 * b0], xbc0 = cf[2 * b0 + 1];
    const float xbr1 = cf[2 * b1], xbc1 = cf[2 * b1 + 1];

    for (int a = 0; a < RA; ++a) {
        const int ai = a0 + a;
        const float xar = cf[2 * ai], xac = cf[2 * ai + 1];   // wave-uniform
        const long arow = (long)n * NS + ai;
        float* po = out + arow * NS;

        // ---- slot 0 ----
        {
            float dr = xar - xbr0, dc = xac - xbc0;
            float cd = dr * dr + dc * dc;
            float res = 0.0f;
            if (cd < 30.0f) {
                const float4* pa = (const float4*)(selc + arow * KP);
                const float4* pb = (const float4*)(selc + ((long)n * NS + b0) * KP);
                float dot = 0.0f;
                #pragma unroll
                for (int j = 0; j < 7; ++j) {
                    float4 va = pa[j], vb = pb[j];
                    dot += va.x * vb.x;
                    dot += va.y * vb.y;
                    dot += va.z * vb.z;
                    dot += va.w * vb.w;
                }
                const float* pga = selg + arow * 4;
                const float* pgb = selg + ((long)n * NS + b0) * 4;
                float g0 = pga[0] - pgb[0];
                float g1 = pga[1] - pgb[1];
                float g2 = pga[2] - pgb[2];
                float gd = g0 * g0 + g1 * g1 + g2 * g2;
                float s = 10.0f * __expf(-cd - gd * (1.0f / 0.3f))
                        +  3.0f * __expf(-10.0f * cd);
                res = -dot * s;
            }
            po[b0] = res;
        }
        // ---- slot 1 ----
        {
            float dr = xar - xbr1, dc = xac - xbc1;
            float cd = dr * dr + dc * dc;
            float res = 0.0f;
            if (w1 && cd < 30.0f) {
                const float4* pa = (const float4*)(selc + arow * KP);
                const float4* pb = (const float4*)(selc + ((long)n * NS + b1) * KP);
                float dot = 0.0f;
                #pragma unroll
                for (int j = 0; j < 7; ++j) {
                    float4 va = pa[j], vb = pb[j];
                    dot += va.x * vb.x;
                    dot += va.y * vb.y;
                    dot += va.z * vb.z;
                    dot += va.w * vb.w;
                }
                const float* pga = selg + arow * 4;
                const float* pgb = selg + ((long)n * NS + b1) * 4;
                float g0 = pga[0] - pgb[0];
                float g1 = pga[1] - pgb[1];
                float g2 = pga[2] - pgb[2];
                float gd = g0 * g0 + g1 * g1 + g2 * g2;
                float s = 10.0f * __expf(-cd - gd * (1.0f / 0.3f))
                        +  3.0f * __expf(-10.0f * cd);
                res = -dot * s;
            }
            if (w1) po[b1raw] = res;
        }
    }
}

extern "C" void kernel_launch(void* const* d_in, const int* in_sizes, int n_in,
                              void* d_out, int out_size, void* d_ws, size_t ws_size,
                              hipStream_t stream) {
    const float* guidance = (const float*)d_in[0];
    const float* clusters = (const float*)d_in[1];
    const int*   coords   = (const int*)d_in[2];
    float* out = (float*)d_out;
    float* ws  = (float*)d_ws;

    {
        int total = NB * NS * 32;
        int blocks = (total + 255) / 256;
        crf_gather<<<blocks, 256, 0, stream>>>(guidance, clusters, coords, ws);
    }
    {
        int blocks = NB * NCHUNK;   // 1600
        crf_main<<<blocks, 512, 0, stream>>>(ws, out);
    }
}